// Round 2
// baseline (1496.226 us; speedup 1.0000x reference)
//
#include <hip/hip_runtime.h>
#include <hip/hip_bf16.h>

#define N_NODES 10000
#define N_EDGES 160000
#define MUL0 128
#define MUL1 64
#define FC_IN 8
#define FC_H 64
#define MID 192
#define AGG_W 768
#define FEAT_W 320

__device__ __forceinline__ float gelu_tanh(float x) {
    float x3 = x * x * x;
    float t = tanhf(0.7978845608028654f * (x + 0.044715f * x3));
    return 0.5f * x * (1.0f + t);
}

// ---------------- Kernel 1: node transforms (feat0/feat1/self0/self1) -------
// feat_tbl / self_tbl rows: [0..128) = mul0 part, [128..320) = mul1 part as u*3+i
__global__ __launch_bounds__(256) void node_transform(
    const float* __restrict__ node_input,
    const float* __restrict__ Wa0, const float* __restrict__ Wa1,
    const float* __restrict__ Wb0, const float* __restrict__ Wb1,
    float* __restrict__ feat_tbl, float* __restrict__ self_tbl)
{
    __shared__ float x[FEAT_W];
    const int node = blockIdx.x;
    const float* row = node_input + (size_t)node * FEAT_W;
    for (int t = threadIdx.x; t < FEAT_W; t += 256) x[t] = row[t];
    __syncthreads();

    for (int t = threadIdx.x; t < 640; t += 256) {
        const bool is_self = (t >= 320);
        const int idx = is_self ? t - 320 : t;
        float acc = 0.f;
        if (idx < 128) {
            const float* W = is_self ? Wb0 : Wa0;
            for (int v = 0; v < 128; ++v) acc += x[v] * W[v * 128 + idx];
            acc *= 0.08838834764831845f;  // 1/sqrt(128)
        } else {
            const int r = idx - 128;
            const int u = r / 3;
            const int i = r - 3 * u;
            const float* W = is_self ? Wb1 : Wa1;
            for (int v = 0; v < 64; ++v) acc += x[128 + v * 3 + i] * W[v * 64 + u];
            acc *= 0.125f;  // 1/sqrt(64)
        }
        float* outp = is_self ? self_tbl : feat_tbl;
        outp[(size_t)node * FEAT_W + idx] = acc;
    }
}

// ---------------- Kernel 2: per-edge MLP + tensor product + scatter ---------
// one wave (64 lanes) per edge; 4 edges per 256-thread block
__global__ __launch_bounds__(256) void edge_kernel(
    const float* __restrict__ edge_attr,   // (E,4)
    const float* __restrict__ esa,         // (E,8)
    const float* __restrict__ M1,          // (8,64)
    const float* __restrict__ M2,          // (64,64)
    const float* __restrict__ Wtp0,        // (64,128)
    const float* __restrict__ Wtp1,        // (64,128)
    const float* __restrict__ Wtp2,        // (64,64)
    const float* __restrict__ Wtp3,        // (64,64)
    const int* __restrict__ edge_src, const int* __restrict__ edge_dst,
    const float* __restrict__ feat_tbl,
    float* __restrict__ agg)
{
    __shared__ float sh[4][64];
    const int wave = threadIdx.x >> 6;
    const int lane = threadIdx.x & 63;
    const int e = blockIdx.x * 4 + wave;   // N_EDGES % 4 == 0, no guard needed

    // --- h1 = gelu(esa @ M1 / sqrt(8)) ---
    const float* er = esa + (size_t)e * 8;
    float a[8];
#pragma unroll
    for (int k = 0; k < 8; ++k) a[k] = er[k];
    float h = 0.f;
#pragma unroll
    for (int k = 0; k < 8; ++k) h += a[k] * M1[k * 64 + lane];
    h = gelu_tanh(h * 0.35355339059327373f);
    sh[wave][lane] = h;
    __syncthreads();

    // --- h2 = gelu(h1 @ M2 / 8) ---
    float h2 = 0.f;
    for (int v = 0; v < 64; ++v) h2 += sh[wave][v] * M2[v * 64 + lane];
    h2 = gelu_tanh(h2 * 0.125f);
    __syncthreads();
    sh[wave][lane] = h2;
    __syncthreads();

    // --- w0,w1 (128 wide: u=lane, u=lane+64), w2,w3 (64 wide) ---
    float w0a = 0.f, w0b = 0.f, w1a = 0.f, w1b = 0.f, w2 = 0.f, w3 = 0.f;
    for (int v = 0; v < 64; ++v) {
        const float hv = sh[wave][v];
        w0a += hv * Wtp0[v * 128 + lane];
        w0b += hv * Wtp0[v * 128 + 64 + lane];
        w1a += hv * Wtp1[v * 128 + lane];
        w1b += hv * Wtp1[v * 128 + 64 + lane];
        w2  += hv * Wtp2[v * 64 + lane];
        w3  += hv * Wtp3[v * 64 + lane];
    }
    const float s8 = 0.125f;  // 1/sqrt(64)
    w0a *= s8; w0b *= s8; w1a *= s8; w1b *= s8; w2 *= s8; w3 *= s8;

    // --- gather ---
    const int src = edge_src[e];
    const int dst = edge_dst[e];
    const float* f = feat_tbl + (size_t)src * FEAT_W;
    const float e0a = f[lane];
    const float e0b = f[64 + lane];
    float e1[3];
#pragma unroll
    for (int i = 0; i < 3; ++i) e1[i] = f[128 + lane * 3 + i];
    const float y0 = edge_attr[(size_t)e * 4];
    float y1[3];
#pragma unroll
    for (int i = 0; i < 3; ++i) y1[i] = edge_attr[(size_t)e * 4 + 1 + i];

    // --- tensor product + scatter ---
    float* arow = agg + (size_t)dst * AGG_W;
    atomicAdd(arow + lane,      w0a * e0a * y0);                       // mid0a
    atomicAdd(arow + 64 + lane, w0b * e0b * y0);
    const float dot = e1[0] * y1[0] + e1[1] * y1[1] + e1[2] * y1[2];
    atomicAdd(arow + 128 + lane, w3 * dot * 0.5773502691896258f);      // mid0b
#pragma unroll
    for (int i = 0; i < 3; ++i) {
        atomicAdd(arow + 192 + lane * 3 + i,        w1a * e0a * y1[i]); // mid1a
        atomicAdd(arow + 192 + (64 + lane) * 3 + i, w1b * e0b * y1[i]);
        atomicAdd(arow + 576 + lane * 3 + i,        w2 * e1[i] * y0);   // mid1b
    }
}

// ---------------- Kernel 3: output GEMMs + combine --------------------------
__global__ __launch_bounds__(256) void out_kernel(
    const float* __restrict__ agg, const float* __restrict__ self_tbl,
    const float* __restrict__ Wo0,   // (192,128)
    const float* __restrict__ Wo1,   // (192,64)
    float* __restrict__ out)
{
    __shared__ float z[AGG_W];
    const int node = blockIdx.x;
    const float* ar = agg + (size_t)node * AGG_W;
    for (int t = threadIdx.x; t < AGG_W; t += 256) z[t] = ar[t] * 0.25f;  // 1/sqrt(16)
    __syncthreads();

    const float sA = 0.07216878364870323f;   // 1/sqrt(192)
    const float c = 0.92387953251128674f;    // cos(pi/8)
    const float s = 0.38268343236508978f;    // sin(pi/8)

    for (int t = threadIdx.x; t < 320; t += 256) {
        float acc = 0.f;
        if (t < 128) {
            for (int v = 0; v < 192; ++v) acc += z[v] * Wo0[v * 128 + t];
        } else {
            const int r = t - 128;
            const int u = r / 3;
            const int i = r - 3 * u;
            // z1[v][i]: v<128 from mid1a block, v>=128 from mid1b block
            for (int v = 0; v < 128; ++v) acc += z[192 + v * 3 + i] * Wo1[v * 64 + u];
            for (int v = 0; v < 64; ++v)  acc += z[576 + v * 3 + i] * Wo1[(128 + v) * 64 + u];
        }
        acc *= sA;
        const float sv = self_tbl[(size_t)node * FEAT_W + t];
        out[(size_t)node * FEAT_W + t] = c * sv + s * acc;
    }
}

extern "C" void kernel_launch(void* const* d_in, const int* in_sizes, int n_in,
                              void* d_out, int out_size, void* d_ws, size_t ws_size,
                              hipStream_t stream) {
    const float* node_input = (const float*)d_in[0];
    const float* edge_attr  = (const float*)d_in[1];
    const float* esa        = (const float*)d_in[2];
    const float* Wa0  = (const float*)d_in[3];
    const float* Wa1  = (const float*)d_in[4];
    const float* Wb0  = (const float*)d_in[5];
    const float* Wb1  = (const float*)d_in[6];
    const float* M1   = (const float*)d_in[7];
    const float* M2   = (const float*)d_in[8];
    const float* Wtp0 = (const float*)d_in[9];
    const float* Wtp1 = (const float*)d_in[10];
    const float* Wtp2 = (const float*)d_in[11];
    const float* Wtp3 = (const float*)d_in[12];
    const float* Wo0  = (const float*)d_in[13];
    const float* Wo1  = (const float*)d_in[14];
    const int* edge_src = (const int*)d_in[15];
    const int* edge_dst = (const int*)d_in[16];
    float* out = (float*)d_out;

    float* feat_tbl = (float*)d_ws;                              // 10000*320 f32
    float* self_tbl = feat_tbl + (size_t)N_NODES * FEAT_W;       // 10000*320 f32
    float* agg      = self_tbl + (size_t)N_NODES * FEAT_W;       // 10000*768 f32

    hipMemsetAsync(agg, 0, sizeof(float) * (size_t)N_NODES * AGG_W, stream);

    node_transform<<<N_NODES, 256, 0, stream>>>(node_input, Wa0, Wa1, Wb0, Wb1,
                                                feat_tbl, self_tbl);
    edge_kernel<<<N_EDGES / 4, 256, 0, stream>>>(edge_attr, esa, M1, M2,
                                                 Wtp0, Wtp1, Wtp2, Wtp3,
                                                 edge_src, edge_dst, feat_tbl, agg);
    out_kernel<<<N_NODES, 256, 0, stream>>>(agg, self_tbl, Wo0, Wo1, out);
}